// Round 13
// baseline (35.480 us; speedup 1.0000x reference)
//
#include <hip/hip_runtime.h>
#include <cstdint>

// Problem constants (from setup_inputs: logits/targets [16,1,512,512] f32)
#define BB 16
#define HH 512
#define WW 512
#define NPIX (BB*HH*WW)          // 4194304
#define WPR (WW/32)              // 16 words per row
#define NHW (BB*HH*WPR)          // 131072 u32 = 512 KB horizontal bitmask
#define PXT 4                    // pixels per thread (consecutive columns)
#define NGRP (NPIX/PXT/512)      // 2048 blocks (512 threads, 4 rows x 128 col-grps)
#define NXCD 8

// ---------------------------------------------------------------------------
// Kernel 0: horizontal bit-pack via wave ballot. hm flat index = px/32, i.e.
// hm[b][i][j/32] bit (j&31) = (targets[b][i][j] > 0.5). One coalesced load +
// one ballot per 64 px.
// ---------------------------------------------------------------------------
__global__ __launch_bounds__(256) void packball(const float* __restrict__ targets,
                                                uint32_t* __restrict__ hm) {
    const int px = blockIdx.x * 256 + threadIdx.x;
    const unsigned long long m = __ballot(targets[px] > 0.5f);
    const int lane = threadIdx.x & 63;
    if (lane == 0)       hm[px >> 5] = (uint32_t)m;
    else if (lane == 32) hm[px >> 5] = (uint32_t)(m >> 32);
}

// ---------------------------------------------------------------------------
// Nearest-opposite |dj| within one row (exact): 64-bit window [j-o-32, j+63-o]
// via 3 words + ffs/clz; word-scan fallback beyond (P ~ 2^-32, exactness).
// tm = t ? ~0 : 0 so (S ^ tm) has 1-bits exactly at opposite pixels; vl/vh
// zero out out-of-image words. Also checks dj == 0 (bit o of center word).
// ---------------------------------------------------------------------------
__device__ __forceinline__ int rowcheck_dj(const uint32_t* __restrict__ hrow,
                                           int widx, int o, int j,
                                           uint32_t tm, uint32_t vl, uint32_t vh) {
    const uint32_t Sc = hrow[widx];
    const uint32_t Sl = vl ? hrow[widx - 1] : 0u;
    const uint32_t Sh = vh ? hrow[widx + 1] : 0u;
    const uint32_t Oc = Sc ^ tm;
    const uint32_t Ol = (Sl ^ tm) & vl;
    const uint32_t Oh = (Sh ^ tm) & vh;
    // right: distances 1 .. 63-o
    const uint64_t Zr = ((uint64_t)Oc >> (o + 1)) | ((uint64_t)Oh << (31 - o));
    // left: bit63 = column j-1, descending, down to j-(o+32)
    const uint64_t Zl = (((uint64_t)Oc << 32) | (uint64_t)Ol) << (32 - o);

    int dr, dl;
    if (Zr) {
        dr = __ffsll((unsigned long long)Zr);
    } else {                                   // essentially never
        dr = 1023;
        for (int ww = widx + 2; ww < WPR; ++ww) {
            const uint32_t Ow = hrow[ww] ^ tm;
            if (Ow) { dr = 32 * ww + (__ffs(Ow) - 1) - j; break; }
        }
    }
    if (Zl) {
        dl = __clzll((long long)Zl) + 1;
    } else {                                   // essentially never
        dl = 1023;
        for (int ww = widx - 2; ww >= 0; --ww) {
            const uint32_t Ow = hrow[ww] ^ tm;
            if (Ow) { dl = j - (32 * ww + 31 - __clz((int)Ow)); break; }
        }
    }
    int dj = min(dr, dl);
    dj = min(dj, ((Oc >> o) & 1u) ? 0 : 1023);
    return dj;
}

// ---------------------------------------------------------------------------
// 2D EDT ring-search kernel: each thread owns 4 consecutive pixels of a row.
// best(px) = min over di of di^2 + rowdj(i+-di)^2, expanding di until
// di^2 >= best (exact: farther rows contribute >= di^2). For random data the
// loop body runs for di=0 and di=1 only (~3 row-checks). No LDS staging, no
// barriers, no intermediate d1 pass. dt = sqrt(best); loss = clip(sigmoid).
// No atomics/fences (round-7 lesson). XCD swizzle for L2 row locality.
// ---------------------------------------------------------------------------
__global__ __launch_bounds__(512) void edt2d(const uint32_t* __restrict__ hm,
                                             const float* __restrict__ logits,
                                             float* __restrict__ partial) {
    const int bid = blockIdx.x;
    const int g   = (bid & (NXCD - 1)) * (NGRP / NXCD) + (bid >> 3);  // bijective
    const int b   = g >> 7;                  // 128 groups per image
    const int i0  = (g & 127) << 2;          // 4 rows per block
    const int tid = threadIdx.x;
    const int r   = tid >> 7;                // 0..3
    const int i   = i0 + r;
    const int jq  = (tid & 127) << 2;        // first column of this thread
    const int widx = jq >> 5;
    const int ob  = jq & 31;                 // 0,4,...,28 (ob+3 <= 31)
    const uint32_t vl = (widx > 0)       ? 0xFFFFFFFFu : 0u;
    const uint32_t vh = (widx < WPR - 1) ? 0xFFFFFFFFu : 0u;

    const uint32_t* hmb    = hm + (size_t)b * HH * WPR;
    const uint32_t* hrow_i = hmb + i * WPR;

    // vectorized logits load (overlaps the search)
    const float4 x4 = *(const float4*)(logits + ((size_t)(b * HH + i)) * WW + jq);

    const uint32_t Sc0 = hrow_i[widx];
    int best[PXT];
    uint32_t tmv[PXT];

    // di = 0 (own row; dj=0 bit is self and always 0 after XOR)
    #pragma unroll
    for (int q = 0; q < PXT; ++q) {
        const int o = ob + q;
        const uint32_t tm = ((Sc0 >> o) & 1u) ? 0xFFFFFFFFu : 0u;
        tmv[q] = tm;
        const int dj = rowcheck_dj(hrow_i, widx, o, jq + q, tm, vl, vh);
        best[q] = dj * dj;
    }

    // expanding ring over rows
    for (int di = 1; di < HH; ++di) {
        int bmax = best[0];
        #pragma unroll
        for (int q = 1; q < PXT; ++q) bmax = max(bmax, best[q]);
        if (di * di >= bmax) break;
        const int di2 = di * di;
        const int iu = i - di, idn = i + di;
        if (iu >= 0) {
            const uint32_t* hrow = hmb + iu * WPR;
            #pragma unroll
            for (int q = 0; q < PXT; ++q) {
                const int dj = rowcheck_dj(hrow, widx, ob + q, jq + q, tmv[q], vl, vh);
                best[q] = min(best[q], di2 + dj * dj);
            }
        }
        if (idn < HH) {
            const uint32_t* hrow = hmb + idn * WPR;
            #pragma unroll
            for (int q = 0; q < PXT; ++q) {
                const int dj = rowcheck_dj(hrow, widx, ob + q, jq + q, tmv[q], vl, vh);
                best[q] = min(best[q], di2 + dj * dj);
            }
        }
    }

    // loss terms
    float v = 0.0f;
    #pragma unroll
    for (int q = 0; q < PXT; ++q) {
        const float dt = __builtin_amdgcn_sqrtf((float)best[q]);
        const float x  = (q == 0) ? x4.x : (q == 1) ? x4.y : (q == 2) ? x4.z : x4.w;
        float pr = __builtin_amdgcn_rcpf(1.0f + __expf(-x));
        pr = fminf(fmaxf(pr, 1e-7f), (float)(1.0 - 1e-7));
        v += pr * dt;
    }

    // block reduction (512 threads = 8 waves)
    #pragma unroll
    for (int off = 32; off > 0; off >>= 1)
        v += __shfl_down(v, off);

    __shared__ float sw[8];
    const int lane = tid & 63;
    const int wid  = tid >> 6;
    if (lane == 0) sw[wid] = v;
    __syncthreads();
    if (tid == 0) {
        float s = 0.0f;
        #pragma unroll
        for (int ww = 0; ww < 8; ++ww) s += sw[ww];
        partial[g] = s;
    }
}

// ---------------------------------------------------------------------------
// Deterministic final reduction of NGRP (2048) partials -> mean
// ---------------------------------------------------------------------------
__global__ __launch_bounds__(512) void finalreduce(
        const float* __restrict__ partial,
        float* __restrict__ out) {
    const float4 q = ((const float4*)partial)[threadIdx.x];   // 512*4 == 2048
    float v = (q.x + q.y) + (q.z + q.w);

    #pragma unroll
    for (int off = 32; off > 0; off >>= 1)
        v += __shfl_down(v, off);

    __shared__ float sw[8];
    const int lane = threadIdx.x & 63;
    const int wid  = threadIdx.x >> 6;
    if (lane == 0) sw[wid] = v;
    __syncthreads();
    if (threadIdx.x == 0) {
        float s = 0.0f;
        #pragma unroll
        for (int ww = 0; ww < 8; ++ww) s += sw[ww];
        out[0] = s * (1.0f / (float)NPIX);
    }
}

extern "C" void kernel_launch(void* const* d_in, const int* in_sizes, int n_in,
                              void* d_out, int out_size, void* d_ws, size_t ws_size,
                              hipStream_t stream) {
    const float* logits  = (const float*)d_in[0];
    const float* targets = (const float*)d_in[1];
    float* out = (float*)d_out;

    // workspace layout: [ hm u32 NHW (512KB) | partial float NGRP (8KB) ]
    uint32_t* hm   = (uint32_t*)d_ws;
    float* partial = (float*)((char*)d_ws + (size_t)NHW * sizeof(uint32_t));

    packball<<<NPIX / 256, 256, 0, stream>>>(targets, hm);
    edt2d<<<NGRP, 512, 0, stream>>>(hm, logits, partial);
    finalreduce<<<1, 512, 0, stream>>>(partial, out);
}

// Round 14
// 29.365 us; speedup vs baseline: 1.2082x; 1.2082x over previous
//
#include <hip/hip_runtime.h>
#include <cstdint>

// Problem constants (from setup_inputs: logits/targets [16,1,512,512] f32)
#define BB 16
#define HH 512
#define WW 512
#define NPIX (BB*HH*WW)          // 4194304
#define WR (HH/32)               // 16 word-rows per image
#define NWORDS (BB*WR*WW)        // 131072 u32 = 512 KB
#define NXCD 8
#define RPB 8                    // rows per block (8-aligned base: p0+7 <= 31)
#define NGRP (BB*HH/RPB)         // 1024 blocks
#define GCHUNK (NGRP/NXCD)       // 128

// ---------------------------------------------------------------------------
// Kernel 0: vertical bit-pack of targets, 2 words per thread via float2 loads.
// vmask[b][w][j] bit r = (targets[b][32w+r][j] > 0.5).  512 KB total.
// ---------------------------------------------------------------------------
__global__ __launch_bounds__(256) void packbits(const float* __restrict__ targets,
                                                uint32_t* __restrict__ vmask) {
    const int flat = blockIdx.x * 256 + threadIdx.x;   // 0..65535
    const int jp = (flat & 255) * 2;                   // even column
    const int w  = (flat >> 8) & (WR - 1);
    const int b  = flat >> 12;
    const float2* base =
        (const float2*)(targets + ((size_t)(b * HH + w * 32)) * WW + jp);
    uint32_t w0 = 0, w1 = 0;
    #pragma unroll
    for (int r = 0; r < 32; ++r) {
        const float2 q = base[r * (WW / 2)];
        w0 |= (q.x > 0.5f ? 1u : 0u) << r;
        w1 |= (q.y > 0.5f ? 1u : 0u) << r;
    }
    ((uint2*)vmask)[flat] = make_uint2(w0, w1);        // 2*flat == b*8192+w*512+jp
}

// ---------------------------------------------------------------------------
// Fused kernel: one block per 8-ROW GROUP (8-aligned rows always share one
// 32-bit word-row), 512 threads = one column each, 8 pixels per thread.
//  Phase 1: the SAME 3 vmask words (self/up/down) serve all 8 rows; per row
//           just shift/ffs/clz on 64-bit windows (exact; word-scan fallback).
//  Phase 2: packed (d<<1)|t in LDS [8][512]; row transform BRANCHLESS k=1..7
//           (horizontal opposites appear as dd=0 candidates, so any k>=8
//           candidate costs >= 64: exact tail loop entered only if m > 64 —
//           requires a ~15x16 same-class blob, never on random data).
//  Phase 3: p = clip(sigmoid(logit)) via rcp; v += p*sqrt(m); one block
//           reduction per 4096 pixels.
// No atomics/fences (round-7 lesson: device-scope fence chain = 204 us).
// No serially-divergent loops on the hot path (round-13 lesson: wave-level
// tail probability is 1-(1-p)^512, so per-pixel-rare loops still stall waves).
// ---------------------------------------------------------------------------
__global__ __launch_bounds__(512) void fused_row8(
        const uint32_t* __restrict__ vmask,
        const float* __restrict__ logits,
        float* __restrict__ partial) {
    const int bid = blockIdx.x;
    const int g   = (bid & (NXCD - 1)) * GCHUNK + (bid >> 3);  // bijective swizzle
    const int b   = g >> 6;                 // 64 groups per image
    const int i0  = (g & 63) << 3;          // first row of the group (8-aligned)
    const int j   = threadIdx.x;
    const int w   = i0 >> 5;                // shared word-row (i0..i0+7 same word)
    const int p0  = i0 & 31;                // in {0,8,16,24}

    __shared__ uint32_t pk_s[RPB][WW];
    __shared__ float    sw[8];

    const uint32_t* vm = vmask + (size_t)b * WR * WW;

    // one word-column triple serves all 8 rows
    const uint32_t Wse = vm[w * WW + j];
    const uint32_t Wup = (w > 0)      ? vm[(w - 1) * WW + j] : 0u;
    const uint32_t Wdn = (w < WR - 1) ? vm[(w + 1) * WW + j] : 0u;

    // logits for the 8 pixels (independent loads, overlap phase 1)
    float xs[RPB];
    #pragma unroll
    for (int r = 0; r < RPB; ++r)
        xs[r] = logits[((size_t)(b * HH + i0 + r)) * WW + j];

    int dpx[RPB], tpx[RPB];
    #pragma unroll
    for (int r = 0; r < RPB; ++r) {
        const int      p  = p0 + r;         // <= 31 always
        const int      i  = i0 + r;
        const int      t  = (int)((Wse >> p) & 1u);
        const uint32_t tm = t ? 0xFFFFFFFFu : 0u;
        const uint32_t Xs = Wse ^ tm;                              // 1 = opposite
        const uint32_t Xu = (w > 0)      ? (Wup ^ tm) : 0u;
        const uint32_t Xd = (w < WR - 1) ? (Wdn ^ tm) : 0u;

        // down window: bit q = row i+1+q (covers rows i+1 .. 32w+63)
        const uint64_t Zd = ((uint64_t)Xs >> (p + 1)) | ((uint64_t)Xd << (31 - p));
        // up window: bit 63 = row i-1, descending (covers rows 32w-32 .. i-1)
        const uint64_t Zu = (((uint64_t)Xs << 32) | (uint64_t)Xu) << (32 - p);

        int dd, du;
        if (Zd) {
            dd = __ffsll((unsigned long long)Zd);      // 1-based == distance
        } else {                                       // essentially never
            dd = 1023;
            for (int ww = w + 2; ww < WR; ++ww) {
                const uint32_t Xw = vm[ww * WW + j] ^ tm;
                if (Xw) { dd = 32 * ww + (__ffs(Xw) - 1) - i; break; }
            }
        }
        if (Zu) {
            du = __clzll((long long)Zu) + 1;
        } else {                                       // essentially never
            du = 1023;
            for (int ww = w - 2; ww >= 0; --ww) {
                const uint32_t Xw = vm[ww * WW + j] ^ tm;
                if (Xw) { du = i - (32 * ww + 31 - __clz((int)Xw)); break; }
            }
        }
        dpx[r] = min(min(dd, du), 1023);
        tpx[r] = t;
        pk_s[r][j] = (uint32_t)((dpx[r] << 1) | t);
    }
    __syncthreads();

    // ---- Phase 2 + 3: eight row transforms, branchless k=1..7 ----
    float v = 0.0f;
    #pragma unroll
    for (int r = 0; r < RPB; ++r) {
        const int t = tpx[r];
        int m = dpx[r] * dpx[r];
        const uint32_t* rowp = &pk_s[r][0];
        #pragma unroll
        for (int k = 1; k <= 7; ++k) {
            const int jl = j - k, jr = j + k;
            const uint32_t pl = rowp[jl >= 0 ? jl : 0];
            const uint32_t pr = rowp[jr < WW ? jr : (WW - 1)];
            const int dl = ((int)(pl & 1u) == t) ? (int)(pl >> 1) : 0;
            const int dr = ((int)(pr & 1u) == t) ? (int)(pr >> 1) : 0;
            const int cl = (jl >= 0) ? (dl * dl + k * k) : 0x7fffffff;
            const int cr = (jr < WW) ? (dr * dr + k * k) : 0x7fffffff;
            m = min(m, min(cl, cr));
        }
        if (m > 64) {   // k>=8 candidates cost >= 64: exact tail, ~never taken
            const int kmaxRow = max(j, WW - 1 - j);
            for (int k = 8; k <= kmaxRow && k * k < m; ++k) {
                const int k2 = k * k;
                if (k <= j) {
                    const uint32_t p2 = rowp[j - k];
                    const int ddx = ((int)(p2 & 1u) == t) ? (int)(p2 >> 1) : 0;
                    const int c = ddx * ddx + k2;
                    m = c < m ? c : m;
                }
                if (k <= WW - 1 - j) {
                    const uint32_t p2 = rowp[j + k];
                    const int ddx = ((int)(p2 & 1u) == t) ? (int)(p2 >> 1) : 0;
                    const int c = ddx * ddx + k2;
                    m = c < m ? c : m;
                }
            }
        }
        const float dt = __builtin_amdgcn_sqrtf((float)m);
        float pr = __builtin_amdgcn_rcpf(1.0f + __expf(-xs[r]));
        pr = fminf(fmaxf(pr, 1e-7f), (float)(1.0 - 1e-7));
        v += pr * dt;
    }

    // ---- block reduction (512 threads = 8 waves), one per 4096 px ----
    #pragma unroll
    for (int off = 32; off > 0; off >>= 1)
        v += __shfl_down(v, off);

    const int lane = threadIdx.x & 63;
    const int wid  = threadIdx.x >> 6;
    if (lane == 0) sw[wid] = v;
    __syncthreads();
    if (threadIdx.x == 0) {
        float s = 0.0f;
        #pragma unroll
        for (int ww = 0; ww < 8; ++ww) s += sw[ww];
        partial[g] = s;
    }
}

// ---------------------------------------------------------------------------
// Deterministic final reduction of NGRP partials -> mean
// ---------------------------------------------------------------------------
__global__ __launch_bounds__(256) void finalreduce(
        const float* __restrict__ partial,
        float* __restrict__ out) {
    const float4 q = ((const float4*)partial)[threadIdx.x];   // 256*4 == 1024
    float v = (q.x + q.y) + (q.z + q.w);

    #pragma unroll
    for (int off = 32; off > 0; off >>= 1)
        v += __shfl_down(v, off);

    __shared__ float sw[4];
    const int lane = threadIdx.x & 63;
    const int wid  = threadIdx.x >> 6;
    if (lane == 0) sw[wid] = v;
    __syncthreads();
    if (threadIdx.x == 0)
        out[0] = ((sw[0] + sw[1]) + (sw[2] + sw[3])) * (1.0f / (float)NPIX);
}

extern "C" void kernel_launch(void* const* d_in, const int* in_sizes, int n_in,
                              void* d_out, int out_size, void* d_ws, size_t ws_size,
                              hipStream_t stream) {
    const float* logits  = (const float*)d_in[0];
    const float* targets = (const float*)d_in[1];
    float* out = (float*)d_out;

    // workspace layout: [ vmask u32 NWORDS (512KB) | partial float NGRP (4KB) ]
    uint32_t* vmask = (uint32_t*)d_ws;
    float* partial  = (float*)((char*)d_ws + (size_t)NWORDS * sizeof(uint32_t));

    packbits<<<NWORDS / 2 / 256, 256, 0, stream>>>(targets, vmask);
    fused_row8<<<NGRP, 512, 0, stream>>>(vmask, logits, partial);
    finalreduce<<<1, 256, 0, stream>>>(partial, out);
}